// Round 1
// baseline (8161.663 us; speedup 1.0000x reference)
//
#include <hip/hip_runtime.h>

#define NN 170000
#define NE 1200000
#define F_IN 128
#define F_HID 256
#define F_OUT 40
#define BN_EPS 1e-5f

// ---------------- degree / norm ----------------
__global__ void degree_kernel(const int* __restrict__ src, const int* __restrict__ dst,
                              float* __restrict__ deg_out, float* __restrict__ deg_in, int E) {
    int e = blockIdx.x * blockDim.x + threadIdx.x;
    if (e < E) {
        atomicAdd(&deg_out[src[e]], 1.0f);
        atomicAdd(&deg_in[dst[e]], 1.0f);
    }
}

__global__ void norm_kernel(float* __restrict__ a, float* __restrict__ b, int N) {
    int i = blockIdx.x * blockDim.x + threadIdx.x;
    if (i < N) {
        a[i] = rsqrtf(fmaxf(a[i], 1.0f));
        b[i] = rsqrtf(fmaxf(b[i], 1.0f));
    }
}

// ---------------- edge aggregation: out[dst] += h[src] * norm_src[src] ----------------
template<int F>
__global__ void aggregate_kernel(const float* __restrict__ h, const int* __restrict__ src,
                                 const int* __restrict__ dst, const float* __restrict__ norm_src,
                                 float* __restrict__ out, int E) {
    constexpr int VPE = F / 4;  // float4 groups per edge
    unsigned idx = blockIdx.x * blockDim.x + threadIdx.x;
    unsigned total = (unsigned)E * VPE;
    if (idx >= total) return;
    unsigned e = idx / VPE;
    unsigned g = idx % VPE;
    int s = src[e], d = dst[e];
    float ns = norm_src[s];
    const float4 v = *(const float4*)(h + (size_t)s * F + g * 4);
    float* o = out + (size_t)d * F + g * 4;
    atomicAdd(o + 0, v.x * ns);
    atomicAdd(o + 1, v.y * ns);
    atomicAdd(o + 2, v.z * ns);
    atomicAdd(o + 3, v.w * ns);
}

// ---------------- fp32 GEMM: C[N x M] = A[N x K] @ W[K x M], optional row scale ----------------
template<int K, int M, bool SCALE>
__global__ __launch_bounds__(256) void gemm_kernel(const float* __restrict__ A,
                                                   const float* __restrict__ W,
                                                   const float* __restrict__ norm_dst,
                                                   float* __restrict__ C, int N) {
    __shared__ float As[16][68];  // [k][row], padded for alignment
    __shared__ float Ws[16][64];  // [k][col]
    const int tx = threadIdx.x % 16;
    const int ty = threadIdx.x / 16;
    const int r0 = blockIdx.y * 64;
    const int m0 = blockIdx.x * 64;
    float acc[4][4] = {};

    for (int k0 = 0; k0 < K; k0 += 16) {
        // A tile: 64 rows x 16 k
        #pragma unroll
        for (int l = 0; l < 4; l++) {
            int id = threadIdx.x + l * 256;
            int r = id / 16, c = id % 16;
            int row = r0 + r;
            As[c][r] = (row < N) ? A[(size_t)row * K + k0 + c] : 0.0f;
        }
        // W tile: 16 k x 64 cols
        #pragma unroll
        for (int l = 0; l < 4; l++) {
            int id = threadIdx.x + l * 256;
            int k = id / 64, m = id % 64;
            int col = m0 + m;
            Ws[k][m] = (col < M) ? W[(size_t)(k0 + k) * M + col] : 0.0f;
        }
        __syncthreads();
        #pragma unroll
        for (int kk = 0; kk < 16; kk++) {
            float a[4], b[4];
            #pragma unroll
            for (int i = 0; i < 4; i++) a[i] = As[kk][ty * 4 + i];
            #pragma unroll
            for (int j = 0; j < 4; j++) b[j] = Ws[kk][tx * 4 + j];
            #pragma unroll
            for (int i = 0; i < 4; i++)
                #pragma unroll
                for (int j = 0; j < 4; j++)
                    acc[i][j] += a[i] * b[j];
        }
        __syncthreads();
    }

    #pragma unroll
    for (int i = 0; i < 4; i++) {
        int row = r0 + ty * 4 + i;
        if (row >= N) continue;
        float scale = SCALE ? norm_dst[row] : 1.0f;
        #pragma unroll
        for (int j = 0; j < 4; j++) {
            int col = m0 + tx * 4 + j;
            if (col < M) C[(size_t)row * M + col] = acc[i][j] * scale;
        }
    }
}

// ---------------- BatchNorm ----------------
__global__ void bn_stats_kernel(const float* __restrict__ h, int N,
                                float* __restrict__ sum, float* __restrict__ sumsq) {
    int col = threadIdx.x;  // 256 threads = 256 columns
    float s = 0.0f, ss = 0.0f;
    for (int i = blockIdx.x; i < N; i += gridDim.x) {
        float v = h[(size_t)i * 256 + col];
        s += v;
        ss += v * v;
    }
    atomicAdd(&sum[col], s);
    atomicAdd(&sumsq[col], ss);
}

__global__ void bn_apply_relu_kernel(float* __restrict__ h, int N,
                                     const float* __restrict__ sum, const float* __restrict__ sumsq,
                                     const float* __restrict__ gamma, const float* __restrict__ beta) {
    unsigned idx = blockIdx.x * blockDim.x + threadIdx.x;
    if (idx >= (unsigned)N * 256u) return;
    int col = idx & 255;
    float invN = 1.0f / (float)N;
    float mean = sum[col] * invN;
    float var = sumsq[col] * invN - mean * mean;
    float inv = rsqrtf(var + BN_EPS);
    float v = h[idx];
    v = (v - mean) * inv * gamma[col] + beta[col];
    h[idx] = fmaxf(v, 0.0f);
}

// ---------------- final: out = out * norm_dst[row] + b2[col] ----------------
__global__ void finalize_kernel(float* __restrict__ out, const float* __restrict__ norm_dst,
                                const float* __restrict__ b2, int N) {
    unsigned idx = blockIdx.x * blockDim.x + threadIdx.x;
    if (idx >= (unsigned)N * F_OUT) return;
    unsigned i = idx / F_OUT;
    unsigned f = idx % F_OUT;
    out[idx] = out[idx] * norm_dst[i] + b2[f];
}

extern "C" void kernel_launch(void* const* d_in, const int* in_sizes, int n_in,
                              void* d_out, int out_size, void* d_ws, size_t ws_size,
                              hipStream_t stream) {
    const float* feat  = (const float*)d_in[0];
    const int*   src   = (const int*)d_in[1];
    const int*   dst   = (const int*)d_in[2];
    const float* W0    = (const float*)d_in[3];
    const float* W1    = (const float*)d_in[4];
    const float* W2    = (const float*)d_in[5];
    const float* b2    = (const float*)d_in[6];
    const float* g0    = (const float*)d_in[7];
    const float* beta0 = (const float*)d_in[8];
    const float* g1    = (const float*)d_in[9];
    const float* beta1 = (const float*)d_in[10];
    float* out = (float*)d_out;

    const int N = NN, E = NE;

    // workspace carve (256B aligned regions)
    char* ws = (char*)d_ws;
    auto alloc_f = [&](size_t nfloats) {
        float* p = (float*)ws;
        ws += ((nfloats * sizeof(float) + 255) / 256) * 256;
        return p;
    };
    float* norm_src = alloc_f(N);          // degrees then norms, in-place
    float* norm_dst = alloc_f(N);
    float* bnsum    = alloc_f(512);        // [0:256) sum, [256:512) sumsq
    float* bufA     = alloc_f((size_t)N * F_HID);
    float* bufB     = alloc_f((size_t)N * F_HID);
    float* bnsumsq  = bnsum + 256;

    // degrees -> norms
    hipMemsetAsync(norm_src, 0, (size_t)N * 4, stream);
    hipMemsetAsync(norm_dst, 0, (size_t)N * 4, stream);
    degree_kernel<<<(E + 255) / 256, 256, 0, stream>>>(src, dst, norm_src, norm_dst, E);
    norm_kernel<<<(N + 255) / 256, 256, 0, stream>>>(norm_src, norm_dst, N);

    // ---- layer 0: aggregate feat (width 128), then GEMM0 (scale by norm_dst), BN+ReLU
    hipMemsetAsync(bufA, 0, (size_t)N * F_IN * 4, stream);
    {
        unsigned total = (unsigned)E * (F_IN / 4);
        aggregate_kernel<F_IN><<<(total + 255) / 256, 256, 0, stream>>>(feat, src, dst, norm_src, bufA, E);
    }
    {
        dim3 grid(F_HID / 64, (N + 63) / 64);
        gemm_kernel<F_IN, F_HID, true><<<grid, 256, 0, stream>>>(bufA, W0, norm_dst, bufB, N);
    }
    hipMemsetAsync(bnsum, 0, 512 * 4, stream);
    bn_stats_kernel<<<512, 256, 0, stream>>>(bufB, N, bnsum, bnsumsq);
    bn_apply_relu_kernel<<<N, 256, 0, stream>>>(bufB, N, bnsum, bnsumsq, g0, beta0);

    // ---- layer 1: aggregate h0 (width 256), GEMM1 (scale), BN+ReLU
    hipMemsetAsync(bufA, 0, (size_t)N * F_HID * 4, stream);
    {
        unsigned total = (unsigned)E * (F_HID / 4);
        aggregate_kernel<F_HID><<<(total + 255) / 256, 256, 0, stream>>>(bufB, src, dst, norm_src, bufA, E);
    }
    {
        dim3 grid(F_HID / 64, (N + 63) / 64);
        gemm_kernel<F_HID, F_HID, true><<<grid, 256, 0, stream>>>(bufA, W1, norm_dst, bufB, N);
    }
    hipMemsetAsync(bnsum, 0, 512 * 4, stream);
    bn_stats_kernel<<<512, 256, 0, stream>>>(bufB, N, bnsum, bnsumsq);
    bn_apply_relu_kernel<<<N, 256, 0, stream>>>(bufB, N, bnsum, bnsumsq, g1, beta1);

    // ---- layer 2: project to 40 first, then aggregate into out, then scale+bias
    {
        dim3 grid(1, (N + 63) / 64);
        gemm_kernel<F_HID, F_OUT, false><<<grid, 256, 0, stream>>>(bufB, W2, nullptr, bufA, N);
    }
    hipMemsetAsync(out, 0, (size_t)N * F_OUT * 4, stream);
    {
        unsigned total = (unsigned)E * (F_OUT / 4);
        aggregate_kernel<F_OUT><<<(total + 255) / 256, 256, 0, stream>>>(bufA, src, dst, norm_src, out, E);
    }
    finalize_kernel<<<((unsigned)N * F_OUT + 255) / 256, 256, 0, stream>>>(out, norm_dst, b2, N);
}

// Round 3
// 1603.128 us; speedup vs baseline: 5.0911x; 5.0911x over previous
//
#include <hip/hip_runtime.h>

#define NN 170000
#define NE 1200000
#define F_IN 128
#define F_HID 256
#define F_OUT 40
#define BN_EPS 1e-5f
#define SCAN_B ((NN + 255) / 256)   // 665 partial blocks

// ---------------- bf16 helpers (manual, RNE) ----------------
__device__ __forceinline__ float b2f(unsigned short u) {
    union { unsigned x; float f; } c; c.x = ((unsigned)u) << 16; return c.f;
}
__device__ __forceinline__ unsigned short f2b(float f) {
    union { float f; unsigned x; } c; c.f = f;
    unsigned r = (c.x + 0x7FFFu + ((c.x >> 16) & 1u)) >> 16;
    return (unsigned short)r;
}

// ---------------- CSR construction ----------------
__global__ void count_kernel(const int* __restrict__ src, const int* __restrict__ dst,
                             int* __restrict__ cnt_src, int* __restrict__ cnt_dst, int E) {
    int e = blockIdx.x * blockDim.x + threadIdx.x;
    if (e < E) {
        atomicAdd(&cnt_src[src[e]], 1);
        atomicAdd(&cnt_dst[dst[e]], 1);
    }
}

__global__ void norm_kernel(const int* __restrict__ cnt_src, const int* __restrict__ cnt_dst,
                            float* __restrict__ norm_src, float* __restrict__ norm_dst, int N) {
    int i = blockIdx.x * blockDim.x + threadIdx.x;
    if (i < N) {
        norm_src[i] = rsqrtf((float)max(cnt_src[i], 1));
        norm_dst[i] = rsqrtf((float)max(cnt_dst[i], 1));
    }
}

__global__ void scan_block_kernel(const int* __restrict__ cnt, int* __restrict__ local,
                                  int* __restrict__ partials, int N) {
    __shared__ int s[256];
    int t = threadIdx.x;
    int idx = blockIdx.x * 256 + t;
    int v = (idx < N) ? cnt[idx] : 0;
    s[t] = v;
    __syncthreads();
    #pragma unroll
    for (int off = 1; off < 256; off <<= 1) {
        int x = (t >= off) ? s[t - off] : 0;
        __syncthreads();
        s[t] += x;
        __syncthreads();
    }
    if (idx < N) local[idx] = s[t] - v;
    if (t == 255) partials[blockIdx.x] = s[t];
}

__global__ void scan_partials_kernel(int* __restrict__ partials, int B) {
    __shared__ int s[1024];
    int t = threadIdx.x;
    int v = (t < B) ? partials[t] : 0;
    s[t] = v;
    __syncthreads();
    #pragma unroll
    for (int off = 1; off < 1024; off <<= 1) {
        int x = (t >= off) ? s[t - off] : 0;
        __syncthreads();
        s[t] += x;
        __syncthreads();
    }
    if (t < B) partials[t] = s[t] - v;
}

__global__ void scan_add_kernel(const int* __restrict__ local, const int* __restrict__ partials,
                                int* __restrict__ row_ptr, int N) {
    int idx = blockIdx.x * blockDim.x + threadIdx.x;
    if (idx < N) row_ptr[idx] = local[idx] + partials[idx >> 8];
    if (idx == 0) row_ptr[N] = NE;
}

__global__ void fill_kernel(const int* __restrict__ src, const int* __restrict__ dst,
                            const int* __restrict__ row_ptr, int* __restrict__ fill,
                            int* __restrict__ csr_src, int E) {
    int e = blockIdx.x * blockDim.x + threadIdx.x;
    if (e < E) {
        int d = dst[e];
        int pos = row_ptr[d] + atomicAdd(&fill[d], 1);
        csr_src[pos] = src[e];
    }
}

// ---------------- CSR gather (f32 input) ----------------
template<int F, bool FINAL>
__global__ void gather_kernel(const float* __restrict__ h, const int* __restrict__ row_ptr,
                              const int* __restrict__ csr_src, const float* __restrict__ norm_src,
                              const float* __restrict__ norm_dst, const float* __restrict__ bias,
                              float* __restrict__ out, int N) {
    constexpr int TPN = F / 4;
    unsigned idx = blockIdx.x * blockDim.x + threadIdx.x;
    if (idx >= (unsigned)N * TPN) return;
    unsigned node = idx / TPN;
    unsigned g = idx % TPN;
    int beg = row_ptr[node], end = row_ptr[node + 1];
    float ax = 0.f, ay = 0.f, az = 0.f, aw = 0.f;
    for (int e = beg; e < end; e++) {
        int s = csr_src[e];
        float ns = norm_src[s];
        const float4 v = *(const float4*)(h + (size_t)s * F + g * 4);
        ax += v.x * ns; ay += v.y * ns; az += v.z * ns; aw += v.w * ns;
    }
    if (FINAL) {
        float nd = norm_dst[node];
        const float4 b = *(const float4*)(bias + g * 4);
        ax = ax * nd + b.x; ay = ay * nd + b.y; az = az * nd + b.z; aw = aw * nd + b.w;
    }
    float4 r; r.x = ax; r.y = ay; r.z = az; r.w = aw;
    *(float4*)(out + (size_t)node * F + g * 4) = r;
}

// ---------------- CSR gather (bf16 input, width 256) ----------------
__global__ void gather_bf16_kernel(const unsigned short* __restrict__ h, const int* __restrict__ row_ptr,
                                   const int* __restrict__ csr_src, const float* __restrict__ norm_src,
                                   float* __restrict__ out, int N) {
    constexpr int TPN = F_HID / 4;
    unsigned idx = blockIdx.x * blockDim.x + threadIdx.x;
    if (idx >= (unsigned)N * TPN) return;
    unsigned node = idx / TPN;
    unsigned g = idx % TPN;
    int beg = row_ptr[node], end = row_ptr[node + 1];
    float ax = 0.f, ay = 0.f, az = 0.f, aw = 0.f;
    for (int e = beg; e < end; e++) {
        int s = csr_src[e];
        float ns = norm_src[s];
        const ushort4 v = *(const ushort4*)(h + (size_t)s * F_HID + g * 4);
        ax += b2f(v.x) * ns; ay += b2f(v.y) * ns; az += b2f(v.z) * ns; aw += b2f(v.w) * ns;
    }
    float4 r; r.x = ax; r.y = ay; r.z = az; r.w = aw;
    *(float4*)(out + (size_t)node * F_HID + g * 4) = r;
}

// ---------------- fp32 GEMM: C[N x M] = A[N x K] @ W[K x M], row scale, optional bf16 store ----
template<int K, int M, bool SCALE, bool BF16OUT>
__global__ __launch_bounds__(256) void gemm_kernel(const float* __restrict__ A,
                                                   const float* __restrict__ W,
                                                   const float* __restrict__ norm_dst,
                                                   float* __restrict__ Cf,
                                                   unsigned short* __restrict__ Cb, int N) {
    __shared__ float As[16][68];
    __shared__ float Ws[16][64];
    const int tx = threadIdx.x % 16;
    const int ty = threadIdx.x / 16;
    const int r0 = blockIdx.y * 64;
    const int m0 = blockIdx.x * 64;
    float acc[4][4] = {};

    for (int k0 = 0; k0 < K; k0 += 16) {
        #pragma unroll
        for (int l = 0; l < 4; l++) {
            int id = threadIdx.x + l * 256;
            int r = id / 16, c = id % 16;
            int row = r0 + r;
            As[c][r] = (row < N) ? A[(size_t)row * K + k0 + c] : 0.0f;
        }
        #pragma unroll
        for (int l = 0; l < 4; l++) {
            int id = threadIdx.x + l * 256;
            int k = id / 64, m = id % 64;
            int col = m0 + m;
            Ws[k][m] = (col < M) ? W[(size_t)(k0 + k) * M + col] : 0.0f;
        }
        __syncthreads();
        #pragma unroll
        for (int kk = 0; kk < 16; kk++) {
            float a[4], b[4];
            #pragma unroll
            for (int i = 0; i < 4; i++) a[i] = As[kk][ty * 4 + i];
            #pragma unroll
            for (int j = 0; j < 4; j++) b[j] = Ws[kk][tx * 4 + j];
            #pragma unroll
            for (int i = 0; i < 4; i++)
                #pragma unroll
                for (int j = 0; j < 4; j++)
                    acc[i][j] += a[i] * b[j];
        }
        __syncthreads();
    }

    #pragma unroll
    for (int i = 0; i < 4; i++) {
        int row = r0 + ty * 4 + i;
        if (row >= N) continue;
        float scale = SCALE ? norm_dst[row] : 1.0f;
        #pragma unroll
        for (int j = 0; j < 4; j++) {
            int col = m0 + tx * 4 + j;
            if (col < M) {
                float v = acc[i][j] * scale;
                if (BF16OUT) Cb[(size_t)row * M + col] = f2b(v);
                else         Cf[(size_t)row * M + col] = v;
            }
        }
    }
}

// ---------------- BatchNorm ----------------
template<bool INBF>
__global__ void bn_stats_kernel(const void* __restrict__ hp, int N,
                                float* __restrict__ sum, float* __restrict__ sumsq) {
    int col = threadIdx.x;
    float s = 0.0f, ss = 0.0f;
    for (int i = blockIdx.x; i < N; i += gridDim.x) {
        float v = INBF ? b2f(((const unsigned short*)hp)[(size_t)i * 256 + col])
                       : ((const float*)hp)[(size_t)i * 256 + col];
        s += v;
        ss += v * v;
    }
    atomicAdd(&sum[col], s);
    atomicAdd(&sumsq[col], ss);
}

template<bool INBF, bool OUTBF>
__global__ void bn_apply_relu_kernel(const void* __restrict__ in, void* __restrict__ outp, int N,
                                     const float* __restrict__ sum, const float* __restrict__ sumsq,
                                     const float* __restrict__ gamma, const float* __restrict__ beta) {
    unsigned idx = blockIdx.x * blockDim.x + threadIdx.x;
    if (idx >= (unsigned)N * 256u) return;
    int col = idx & 255;
    float invN = 1.0f / (float)N;
    float mean = sum[col] * invN;
    float var = sumsq[col] * invN - mean * mean;
    float inv = rsqrtf(var + BN_EPS);
    float v = INBF ? b2f(((const unsigned short*)in)[idx]) : ((const float*)in)[idx];
    v = fmaxf((v - mean) * inv * gamma[col] + beta[col], 0.0f);
    if (OUTBF) ((unsigned short*)outp)[idx] = f2b(v);
    else       ((float*)outp)[idx] = v;
}

extern "C" void kernel_launch(void* const* d_in, const int* in_sizes, int n_in,
                              void* d_out, int out_size, void* d_ws, size_t ws_size,
                              hipStream_t stream) {
    const float* feat  = (const float*)d_in[0];
    const int*   src   = (const int*)d_in[1];
    const int*   dst   = (const int*)d_in[2];
    const float* W0    = (const float*)d_in[3];
    const float* W1    = (const float*)d_in[4];
    const float* W2    = (const float*)d_in[5];
    const float* b2    = (const float*)d_in[6];
    const float* g0    = (const float*)d_in[7];
    const float* beta0 = (const float*)d_in[8];
    const float* g1    = (const float*)d_in[9];
    const float* beta1 = (const float*)d_in[10];
    float* out = (float*)d_out;

    const int N = NN, E = NE;

    // ---- workspace carve (total ~268 MB; round-1's proven footprint was ~349 MB)
    char* ws = (char*)d_ws;
    auto alloc_b = [&](size_t bytes) {
        void* p = (void*)ws;
        ws += ((bytes + 255) / 256) * 256;
        return p;
    };
    float* norm_src = (float*)alloc_b((size_t)N * 4);
    float* norm_dst = (float*)alloc_b((size_t)N * 4);
    int*   row_ptr  = (int*)alloc_b((size_t)(N + 1) * 4);
    int*   csr_src  = (int*)alloc_b((size_t)E * 4);
    float* bnsum    = (float*)alloc_b(512 * 4);
    float* R1       = (float*)alloc_b((size_t)N * F_HID * 4);        // 174 MB, f32 N x 256
    void*  R2       =         alloc_b((size_t)N * F_IN * 4);         // 87 MB, time-shared
    float* bnsumsq  = bnsum + 256;

    float*          R2f = (float*)R2;           // gather0 out (N x 128 f32); later GEMM2 out (N x 40 f32)
    unsigned short* R2b = (unsigned short*)R2;  // h bf16 (N x 256)

    // transient CSR-build scratch aliased inside R1 (dead before GEMM0 writes R1)
    int* cnt_src  = (int*)R1;
    int* cnt_dst  = cnt_src + N;
    int* fill     = cnt_dst + N;
    int* local    = fill + N;
    int* partials = local + N;   // 1024 ints

    // ---- CSR build + norms
    hipMemsetAsync(cnt_src, 0, ((size_t)4 * N + 1024) * 4, stream);
    count_kernel<<<(E + 255) / 256, 256, 0, stream>>>(src, dst, cnt_src, cnt_dst, E);
    norm_kernel<<<(N + 255) / 256, 256, 0, stream>>>(cnt_src, cnt_dst, norm_src, norm_dst, N);
    scan_block_kernel<<<SCAN_B, 256, 0, stream>>>(cnt_dst, local, partials, N);
    scan_partials_kernel<<<1, 1024, 0, stream>>>(partials, SCAN_B);
    scan_add_kernel<<<(N + 255) / 256, 256, 0, stream>>>(local, partials, row_ptr, N);
    fill_kernel<<<(E + 255) / 256, 256, 0, stream>>>(src, dst, row_ptr, fill, csr_src, E);

    // ---- layer 0: gather feat (128) -> R2f, GEMM0 (xnorm_dst) -> R1, BN stats, BN+ReLU -> R2b (bf16)
    {
        unsigned total = (unsigned)N * (F_IN / 4);
        gather_kernel<F_IN, false><<<(total + 255) / 256, 256, 0, stream>>>(
            feat, row_ptr, csr_src, norm_src, nullptr, nullptr, R2f, N);
    }
    {
        dim3 grid(F_HID / 64, (N + 63) / 64);
        gemm_kernel<F_IN, F_HID, true, false><<<grid, 256, 0, stream>>>(R2f, W0, norm_dst, R1, nullptr, N);
    }
    hipMemsetAsync(bnsum, 0, 512 * 4, stream);
    bn_stats_kernel<false><<<512, 256, 0, stream>>>(R1, N, bnsum, bnsumsq);
    bn_apply_relu_kernel<false, true><<<((unsigned)N * 256 + 255) / 256, 256, 0, stream>>>(
        R1, R2b, N, bnsum, bnsumsq, g0, beta0);

    // ---- layer 1: gather R2b (bf16, 256) -> R1 (f32 agg), GEMM1 (xnorm_dst) -> R2b (bf16),
    //               BN stats (bf16), BN+ReLU -> R1 (f32 h1)
    {
        unsigned total = (unsigned)N * (F_HID / 4);
        gather_bf16_kernel<<<(total + 255) / 256, 256, 0, stream>>>(
            R2b, row_ptr, csr_src, norm_src, R1, N);
    }
    {
        dim3 grid(F_HID / 64, (N + 63) / 64);
        gemm_kernel<F_HID, F_HID, true, true><<<grid, 256, 0, stream>>>(R1, W1, norm_dst, nullptr, R2b, N);
    }
    hipMemsetAsync(bnsum, 0, 512 * 4, stream);
    bn_stats_kernel<true><<<512, 256, 0, stream>>>(R2b, N, bnsum, bnsumsq);
    bn_apply_relu_kernel<true, false><<<((unsigned)N * 256 + 255) / 256, 256, 0, stream>>>(
        R2b, R1, N, bnsum, bnsumsq, g1, beta1);

    // ---- layer 2: GEMM2 R1 @ W2 -> R2f (N x 40), gather FINAL (xnorm_dst + b2) -> out
    {
        dim3 grid(1, (N + 63) / 64);
        gemm_kernel<F_HID, F_OUT, false, false><<<grid, 256, 0, stream>>>(R1, W2, nullptr, R2f, nullptr, N);
    }
    {
        unsigned total = (unsigned)N * (F_OUT / 4);
        gather_kernel<F_OUT, true><<<(total + 255) / 256, 256, 0, stream>>>(
            R2f, row_ptr, csr_src, norm_src, norm_dst, b2, out, N);
    }
}

// Round 4
// 1164.358 us; speedup vs baseline: 7.0096x; 1.3768x over previous
//
#include <hip/hip_runtime.h>

#define NN 170000
#define NE 1200000
#define F_IN 128
#define F_HID 256
#define F_OUT 40
#define BN_EPS 1e-5f
#define SCAN_B ((NN + 255) / 256)

typedef __attribute__((ext_vector_type(8))) short short8;
typedef __attribute__((ext_vector_type(4))) float f32x4;

// ---------------- bf16 helpers (manual, RNE) ----------------
__device__ __forceinline__ float b2f(unsigned short u) {
    union { unsigned x; float f; } c; c.x = ((unsigned)u) << 16; return c.f;
}
__device__ __forceinline__ unsigned short f2b(float f) {
    union { float f; unsigned x; } c; c.f = f;
    unsigned r = (c.x + 0x7FFFu + ((c.x >> 16) & 1u)) >> 16;
    return (unsigned short)r;
}

// ---------------- CSR construction ----------------
__global__ void count_kernel(const int* __restrict__ src, const int* __restrict__ dst,
                             int* __restrict__ cnt_src, int* __restrict__ cnt_dst, int E) {
    int e = blockIdx.x * blockDim.x + threadIdx.x;
    if (e < E) {
        atomicAdd(&cnt_src[src[e]], 1);
        atomicAdd(&cnt_dst[dst[e]], 1);
    }
}

__global__ void norm_kernel(const int* __restrict__ cnt_src, const int* __restrict__ cnt_dst,
                            float* __restrict__ norm_src, float* __restrict__ norm_dst, int N) {
    int i = blockIdx.x * blockDim.x + threadIdx.x;
    if (i < N) {
        norm_src[i] = rsqrtf((float)max(cnt_src[i], 1));
        norm_dst[i] = rsqrtf((float)max(cnt_dst[i], 1));
    }
}

__global__ void scan_block_kernel(const int* __restrict__ cnt, int* __restrict__ local,
                                  int* __restrict__ partials, int N) {
    __shared__ int s[256];
    int t = threadIdx.x;
    int idx = blockIdx.x * 256 + t;
    int v = (idx < N) ? cnt[idx] : 0;
    s[t] = v;
    __syncthreads();
    #pragma unroll
    for (int off = 1; off < 256; off <<= 1) {
        int x = (t >= off) ? s[t - off] : 0;
        __syncthreads();
        s[t] += x;
        __syncthreads();
    }
    if (idx < N) local[idx] = s[t] - v;
    if (t == 255) partials[blockIdx.x] = s[t];
}

__global__ void scan_partials_kernel(int* __restrict__ partials, int B) {
    __shared__ int s[1024];
    int t = threadIdx.x;
    int v = (t < B) ? partials[t] : 0;
    s[t] = v;
    __syncthreads();
    #pragma unroll
    for (int off = 1; off < 1024; off <<= 1) {
        int x = (t >= off) ? s[t - off] : 0;
        __syncthreads();
        s[t] += x;
        __syncthreads();
    }
    if (t < B) partials[t] = s[t] - v;
}

__global__ void scan_add_kernel(const int* __restrict__ local, const int* __restrict__ partials,
                                int* __restrict__ row_ptr, int N) {
    int idx = blockIdx.x * blockDim.x + threadIdx.x;
    if (idx < N) row_ptr[idx] = local[idx] + partials[idx >> 8];
    if (idx == 0) row_ptr[N] = NE;
}

__global__ void fill_kernel(const int* __restrict__ src, const int* __restrict__ dst,
                            const int* __restrict__ row_ptr, int* __restrict__ fill,
                            int* __restrict__ csr_src, int E) {
    int e = blockIdx.x * blockDim.x + threadIdx.x;
    if (e < E) {
        int d = dst[e];
        int pos = row_ptr[d] + atomicAdd(&fill[d], 1);
        csr_src[pos] = src[e];
    }
}

// ---------------- gather0: f32 in (width 128) -> bf16 out ----------------
__global__ void gather0_kernel(const float* __restrict__ h, const int* __restrict__ row_ptr,
                               const int* __restrict__ csr_src, const float* __restrict__ norm_src,
                               unsigned short* __restrict__ out, int N) {
    constexpr int TPN = F_IN / 4;
    unsigned idx = blockIdx.x * blockDim.x + threadIdx.x;
    if (idx >= (unsigned)N * TPN) return;
    unsigned node = idx / TPN;
    unsigned g = idx % TPN;
    int beg = row_ptr[node], end = row_ptr[node + 1];
    float ax = 0.f, ay = 0.f, az = 0.f, aw = 0.f;
    for (int e = beg; e < end; e++) {
        int s = csr_src[e];
        float ns = norm_src[s];
        const float4 v = *(const float4*)(h + (size_t)s * F_IN + g * 4);
        ax += v.x * ns; ay += v.y * ns; az += v.z * ns; aw += v.w * ns;
    }
    ushort4 o; o.x = f2b(ax); o.y = f2b(ay); o.z = f2b(az); o.w = f2b(aw);
    *(ushort4*)(out + (size_t)node * F_IN + g * 4) = o;
}

// ---------------- gather: bf16 in (width 256) -> bf16 out ----------------
__global__ void gather_bf16_kernel(const unsigned short* __restrict__ h, const int* __restrict__ row_ptr,
                                   const int* __restrict__ csr_src, const float* __restrict__ norm_src,
                                   unsigned short* __restrict__ out, int N) {
    constexpr int TPN = F_HID / 4;
    unsigned idx = blockIdx.x * blockDim.x + threadIdx.x;
    if (idx >= (unsigned)N * TPN) return;
    unsigned node = idx / TPN;
    unsigned g = idx % TPN;
    int beg = row_ptr[node], end = row_ptr[node + 1];
    float ax = 0.f, ay = 0.f, az = 0.f, aw = 0.f;
    for (int e = beg; e < end; e++) {
        int s = csr_src[e];
        float ns = norm_src[s];
        const ushort4 v = *(const ushort4*)(h + (size_t)s * F_HID + g * 4);
        ax += b2f(v.x) * ns; ay += b2f(v.y) * ns; az += b2f(v.z) * ns; aw += b2f(v.w) * ns;
    }
    ushort4 o; o.x = f2b(ax); o.y = f2b(ay); o.z = f2b(az); o.w = f2b(aw);
    *(ushort4*)(out + (size_t)node * F_HID + g * 4) = o;
}

// ---------------- final gather: f32 in (width 40) + norm_dst + bias -> out ----------------
__global__ void gather_final_kernel(const float* __restrict__ h, const int* __restrict__ row_ptr,
                                    const int* __restrict__ csr_src, const float* __restrict__ norm_src,
                                    const float* __restrict__ norm_dst, const float* __restrict__ bias,
                                    float* __restrict__ out, int N) {
    constexpr int TPN = F_OUT / 4;
    unsigned idx = blockIdx.x * blockDim.x + threadIdx.x;
    if (idx >= (unsigned)N * TPN) return;
    unsigned node = idx / TPN;
    unsigned g = idx % TPN;
    int beg = row_ptr[node], end = row_ptr[node + 1];
    float ax = 0.f, ay = 0.f, az = 0.f, aw = 0.f;
    for (int e = beg; e < end; e++) {
        int s = csr_src[e];
        float ns = norm_src[s];
        const float4 v = *(const float4*)(h + (size_t)s * F_OUT + g * 4);
        ax += v.x * ns; ay += v.y * ns; az += v.z * ns; aw += v.w * ns;
    }
    float nd = norm_dst[node];
    const float4 b = *(const float4*)(bias + g * 4);
    float4 r;
    r.x = ax * nd + b.x; r.y = ay * nd + b.y; r.z = az * nd + b.z; r.w = aw * nd + b.w;
    *(float4*)(out + (size_t)node * F_OUT + g * 4) = r;
}

// ---------------- weight transpose+cast: W[K][M] f32 -> Wt[MP][K] bf16 (zero-pad m>=M) ----
template<int K, int M, int MP>
__global__ void wt_kernel(const float* __restrict__ W, unsigned short* __restrict__ Wt) {
    int idx = blockIdx.x * blockDim.x + threadIdx.x;
    if (idx >= MP * K) return;
    int m = idx / K, k = idx % K;
    float v = (m < M) ? W[(size_t)k * M + m] : 0.0f;
    Wt[idx] = f2b(v);
}

// ---------------- MFMA bf16 GEMM: C[N x M_OUT] = A[N x K](bf16) @ Wt^T, optional row scale ----
// Tile: BM=128 rows x BN_T cols, 4 waves; wave = WM_T x WN_T grid of 16x16x32 MFMAs.
template<int K, int BN_T, int WM_T, int WN_T, int WAVES_N, bool SCALE, bool BF16OUT, int M_OUT>
__global__ __launch_bounds__(256) void mfma_gemm(const unsigned short* __restrict__ A,
                                                 const unsigned short* __restrict__ Wt,
                                                 const float* __restrict__ norm_dst,
                                                 void* __restrict__ C, int N) {
    constexpr int BM = 128, BK = 64, AP = 72;  // AP: +8 bf16 pad -> 144 B row stride (16B-aligned, 2-way banks)
    __shared__ unsigned short As[BM * AP];
    __shared__ unsigned short Bs[BN_T * AP];

    const int lane = threadIdx.x & 63;
    const int wave = threadIdx.x >> 6;
    const int wr = wave / WAVES_N, wc = wave % WAVES_N;
    const int quad = lane >> 4, l15 = lane & 15;
    const int r0 = blockIdx.y * BM;
    const int c0 = blockIdx.x * BN_T;
    const int wmb = wr * WM_T * 16;
    const int wnb = wc * WN_T * 16;

    f32x4 acc[WM_T][WN_T] = {};

    for (int k0 = 0; k0 < K; k0 += BK) {
        // stage A tile: BM x BK bf16, 16B chunks
        #pragma unroll
        for (int p = 0; p < BM * (BK / 8) / 256; p++) {
            int c = threadIdx.x + p * 256;
            int row = c >> 3, off = (c & 7) * 8;
            int gr = r0 + row;
            uint4 v = make_uint4(0, 0, 0, 0);
            if (gr < N) v = *(const uint4*)(A + (size_t)gr * K + k0 + off);
            *(uint4*)(As + row * AP + off) = v;
        }
        // stage Bt tile: BN_T cols x BK bf16 (k-contiguous)
        #pragma unroll
        for (int p = 0; p < BN_T * (BK / 8) / 256; p++) {
            int c = threadIdx.x + p * 256;
            int m = c >> 3, off = (c & 7) * 8;
            *(uint4*)(Bs + m * AP + off) = *(const uint4*)(Wt + (size_t)(c0 + m) * K + k0 + off);
        }
        __syncthreads();
        #pragma unroll
        for (int kk = 0; kk < BK; kk += 32) {
            short8 af[WM_T], bf[WN_T];
            #pragma unroll
            for (int i = 0; i < WM_T; i++)
                af[i] = *(const short8*)(As + (wmb + i * 16 + l15) * AP + kk + quad * 8);
            #pragma unroll
            for (int j = 0; j < WN_T; j++)
                bf[j] = *(const short8*)(Bs + (wnb + j * 16 + l15) * AP + kk + quad * 8);
            #pragma unroll
            for (int i = 0; i < WM_T; i++)
                #pragma unroll
                for (int j = 0; j < WN_T; j++)
                    acc[i][j] = __builtin_amdgcn_mfma_f32_16x16x32_bf16(af[i], bf[j], acc[i][j], 0, 0, 0);
        }
        __syncthreads();
    }

    // epilogue: C/D layout col=lane&15, row=quad*4+reg
    #pragma unroll
    for (int i = 0; i < WM_T; i++) {
        #pragma unroll
        for (int r = 0; r < 4; r++) {
            int row = r0 + wmb + i * 16 + quad * 4 + r;
            if (row >= N) continue;
            float scale = SCALE ? norm_dst[row] : 1.0f;
            #pragma unroll
            for (int j = 0; j < WN_T; j++) {
                int col = c0 + wnb + j * 16 + l15;
                if (col < M_OUT) {
                    float v = acc[i][j][r] * scale;
                    if (BF16OUT) ((unsigned short*)C)[(size_t)row * M_OUT + col] = f2b(v);
                    else         ((float*)C)[(size_t)row * M_OUT + col] = v;
                }
            }
        }
    }
}

// ---------------- BatchNorm (bf16 in) ----------------
__global__ void bn_stats_kernel(const unsigned short* __restrict__ h, int N,
                                float* __restrict__ sum, float* __restrict__ sumsq) {
    int col = threadIdx.x;
    float s = 0.0f, ss = 0.0f;
    for (int i = blockIdx.x; i < N; i += gridDim.x) {
        float v = b2f(h[(size_t)i * 256 + col]);
        s += v;
        ss += v * v;
    }
    atomicAdd(&sum[col], s);
    atomicAdd(&sumsq[col], ss);
}

__global__ void bn_apply_relu_kernel(const unsigned short* __restrict__ in, unsigned short* __restrict__ outp,
                                     int N, const float* __restrict__ sum, const float* __restrict__ sumsq,
                                     const float* __restrict__ gamma, const float* __restrict__ beta) {
    unsigned idx = blockIdx.x * blockDim.x + threadIdx.x;
    if (idx >= (unsigned)N * 256u) return;
    int col = idx & 255;
    float invN = 1.0f / (float)N;
    float mean = sum[col] * invN;
    float var = sumsq[col] * invN - mean * mean;
    float inv = rsqrtf(var + BN_EPS);
    float v = b2f(in[idx]);
    v = fmaxf((v - mean) * inv * gamma[col] + beta[col], 0.0f);
    outp[idx] = f2b(v);
}

extern "C" void kernel_launch(void* const* d_in, const int* in_sizes, int n_in,
                              void* d_out, int out_size, void* d_ws, size_t ws_size,
                              hipStream_t stream) {
    const float* feat  = (const float*)d_in[0];
    const int*   src   = (const int*)d_in[1];
    const int*   dst   = (const int*)d_in[2];
    const float* W0    = (const float*)d_in[3];
    const float* W1    = (const float*)d_in[4];
    const float* W2    = (const float*)d_in[5];
    const float* b2    = (const float*)d_in[6];
    const float* g0    = (const float*)d_in[7];
    const float* beta0 = (const float*)d_in[8];
    const float* g1    = (const float*)d_in[9];
    const float* beta1 = (const float*)d_in[10];
    float* out = (float*)d_out;

    const int N = NN, E = NE;

    // ---- workspace carve (~185 MB total; proven budget >= 268 MB)
    char* ws = (char*)d_ws;
    auto alloc_b = [&](size_t bytes) {
        void* p = (void*)ws;
        ws += ((bytes + 255) / 256) * 256;
        return p;
    };
    float* norm_src = (float*)alloc_b((size_t)N * 4);
    float* norm_dst = (float*)alloc_b((size_t)N * 4);
    int*   row_ptr  = (int*)alloc_b((size_t)(N + 1) * 4);
    int*   csr_src  = (int*)alloc_b((size_t)E * 4);
    float* bnsum    = (float*)alloc_b(512 * 4);
    unsigned short* Wt0 = (unsigned short*)alloc_b((size_t)256 * 128 * 2);
    unsigned short* Wt1 = (unsigned short*)alloc_b((size_t)256 * 256 * 2);
    unsigned short* Wt2 = (unsigned short*)alloc_b((size_t)64 * 256 * 2);
    void* P1 = alloc_b((size_t)N * 512);  // N x 256 bf16  OR  N x 40 f32
    void* P2 = alloc_b((size_t)N * 512);
    float* bnsumsq = bnsum + 256;

    unsigned short* P1b = (unsigned short*)P1;
    unsigned short* P2b = (unsigned short*)P2;
    float*          P1f = (float*)P1;

    // CSR-build scratch aliased at head of P1 (dead before gather0 writes P1)
    int* cnt_src  = (int*)P1;
    int* cnt_dst  = cnt_src + N;
    int* fill     = cnt_dst + N;
    int* local    = fill + N;
    int* partials = local + N;

    // ---- CSR build + norms + weight prep
    hipMemsetAsync(cnt_src, 0, ((size_t)4 * N + 1024) * 4, stream);
    count_kernel<<<(E + 255) / 256, 256, 0, stream>>>(src, dst, cnt_src, cnt_dst, E);
    norm_kernel<<<(N + 255) / 256, 256, 0, stream>>>(cnt_src, cnt_dst, norm_src, norm_dst, N);
    scan_block_kernel<<<SCAN_B, 256, 0, stream>>>(cnt_dst, local, partials, N);
    scan_partials_kernel<<<1, 1024, 0, stream>>>(partials, SCAN_B);
    scan_add_kernel<<<(N + 255) / 256, 256, 0, stream>>>(local, partials, row_ptr, N);
    fill_kernel<<<(E + 255) / 256, 256, 0, stream>>>(src, dst, row_ptr, fill, csr_src, E);
    wt_kernel<128, 256, 256><<<(256 * 128 + 255) / 256, 256, 0, stream>>>(W0, Wt0);
    wt_kernel<256, 256, 256><<<(256 * 256 + 255) / 256, 256, 0, stream>>>(W1, Wt1);
    wt_kernel<256, 40, 64><<<(64 * 256 + 255) / 256, 256, 0, stream>>>(W2, Wt2);

    const int GB = (N + 127) / 128;  // 1329 row blocks

    // ---- layer 0
    {
        unsigned total = (unsigned)N * (F_IN / 4);
        gather0_kernel<<<(total + 255) / 256, 256, 0, stream>>>(feat, row_ptr, csr_src, norm_src, P1b, N);
    }
    mfma_gemm<128, 128, 4, 4, 2, true, true, 256><<<dim3(2, GB), 256, 0, stream>>>(P1b, Wt0, norm_dst, P2, N);
    hipMemsetAsync(bnsum, 0, 512 * 4, stream);
    bn_stats_kernel<<<512, 256, 0, stream>>>(P2b, N, bnsum, bnsumsq);
    bn_apply_relu_kernel<<<((unsigned)N * 256 + 255) / 256, 256, 0, stream>>>(P2b, P1b, N, bnsum, bnsumsq, g0, beta0);

    // ---- layer 1
    {
        unsigned total = (unsigned)N * (F_HID / 4);
        gather_bf16_kernel<<<(total + 255) / 256, 256, 0, stream>>>(P1b, row_ptr, csr_src, norm_src, P2b, N);
    }
    mfma_gemm<256, 128, 4, 4, 2, true, true, 256><<<dim3(2, GB), 256, 0, stream>>>(P2b, Wt1, norm_dst, P1, N);
    hipMemsetAsync(bnsum, 0, 512 * 4, stream);
    bn_stats_kernel<<<512, 256, 0, stream>>>(P1b, N, bnsum, bnsumsq);
    bn_apply_relu_kernel<<<((unsigned)N * 256 + 255) / 256, 256, 0, stream>>>(P1b, P2b, N, bnsum, bnsumsq, g1, beta1);

    // ---- layer 2: GEMM2 (M=40, padded 64) -> P1 f32 [N][40], then final gather
    mfma_gemm<256, 64, 2, 4, 1, false, false, 40><<<dim3(1, GB), 256, 0, stream>>>(P2b, Wt2, nullptr, P1, N);
    {
        unsigned total = (unsigned)N * (F_OUT / 4);
        gather_final_kernel<<<(total + 255) / 256, 256, 0, stream>>>(P1f, row_ptr, csr_src, norm_src, norm_dst, b2, out, N);
    }
}

// Round 5
// 881.258 us; speedup vs baseline: 9.2614x; 1.3212x over previous
//
#include <hip/hip_runtime.h>

#define NN 170000
#define NE 1200000
#define F_IN 128
#define F_HID 256
#define F_OUT 40
#define BN_EPS 1e-5f
#define SCAN_B ((NN + 255) / 256)

typedef __attribute__((ext_vector_type(8))) short short8;
typedef __attribute__((ext_vector_type(4))) float f32x4;
typedef __attribute__((ext_vector_type(4))) unsigned short us4;

// ---------------- bf16 helpers (manual, RNE) ----------------
__device__ __forceinline__ float b2f(unsigned short u) {
    union { unsigned x; float f; } c; c.x = ((unsigned)u) << 16; return c.f;
}
__device__ __forceinline__ unsigned short f2b(float f) {
    union { float f; unsigned x; } c; c.f = f;
    unsigned r = (c.x + 0x7FFFu + ((c.x >> 16) & 1u)) >> 16;
    return (unsigned short)r;
}
// BN+ReLU two packed bf16 lanes of one uint
__device__ __forceinline__ unsigned bn2(unsigned u, float a0, float b0, float a1, float b1) {
    float lo = b2f((unsigned short)(u & 0xffffu));
    float hi = b2f((unsigned short)(u >> 16));
    lo = fmaxf(lo * a0 + b0, 0.0f);
    hi = fmaxf(hi * a1 + b1, 0.0f);
    return (unsigned)f2b(lo) | ((unsigned)f2b(hi) << 16);
}

// ---------------- CSR construction ----------------
__global__ void count_kernel(const int* __restrict__ src, const int* __restrict__ dst,
                             int* __restrict__ cnt_src, int* __restrict__ cnt_dst, int E) {
    int e = blockIdx.x * blockDim.x + threadIdx.x;
    if (e < E) {
        atomicAdd(&cnt_src[src[e]], 1);
        atomicAdd(&cnt_dst[dst[e]], 1);
    }
}

__global__ void norm_kernel(const int* __restrict__ cnt_src, const int* __restrict__ cnt_dst,
                            float* __restrict__ norm_src, float* __restrict__ norm_dst, int N) {
    int i = blockIdx.x * blockDim.x + threadIdx.x;
    if (i < N) {
        norm_src[i] = rsqrtf((float)max(cnt_src[i], 1));
        norm_dst[i] = rsqrtf((float)max(cnt_dst[i], 1));
    }
}

__global__ void scan_block_kernel(const int* __restrict__ cnt, int* __restrict__ local,
                                  int* __restrict__ partials, int N) {
    __shared__ int s[256];
    int t = threadIdx.x;
    int idx = blockIdx.x * 256 + t;
    int v = (idx < N) ? cnt[idx] : 0;
    s[t] = v;
    __syncthreads();
    #pragma unroll
    for (int off = 1; off < 256; off <<= 1) {
        int x = (t >= off) ? s[t - off] : 0;
        __syncthreads();
        s[t] += x;
        __syncthreads();
    }
    if (idx < N) local[idx] = s[t] - v;
    if (t == 255) partials[blockIdx.x] = s[t];
}

__global__ void scan_partials_kernel(int* __restrict__ partials, int B) {
    __shared__ int s[1024];
    int t = threadIdx.x;
    int v = (t < B) ? partials[t] : 0;
    s[t] = v;
    __syncthreads();
    #pragma unroll
    for (int off = 1; off < 1024; off <<= 1) {
        int x = (t >= off) ? s[t - off] : 0;
        __syncthreads();
        s[t] += x;
        __syncthreads();
    }
    if (t < B) partials[t] = s[t] - v;
}

__global__ void scan_add_kernel(const int* __restrict__ local, const int* __restrict__ partials,
                                int* __restrict__ row_ptr, int N) {
    int idx = blockIdx.x * blockDim.x + threadIdx.x;
    if (idx < N) row_ptr[idx] = local[idx] + partials[idx >> 8];
    if (idx == 0) row_ptr[N] = NE;
}

__global__ void fill_kernel(const int* __restrict__ src, const int* __restrict__ dst,
                            const int* __restrict__ row_ptr, int* __restrict__ fill,
                            int* __restrict__ csr_src, int E) {
    int e = blockIdx.x * blockDim.x + threadIdx.x;
    if (e < E) {
        int d = dst[e];
        int pos = row_ptr[d] + atomicAdd(&fill[d], 1);
        csr_src[pos] = src[e];
    }
}

// ---------------- feat f32 -> bf16 ----------------
__global__ void cast_feat_kernel(const float* __restrict__ feat, unsigned short* __restrict__ featb) {
    unsigned idx = blockIdx.x * blockDim.x + threadIdx.x;
    if (idx >= (unsigned)NN * (F_IN / 4)) return;
    const float* p = feat + (size_t)idx * 4;
    f32x4 v = __builtin_nontemporal_load((const f32x4*)p);
    us4 o; o.x = f2b(v.x); o.y = f2b(v.y); o.z = f2b(v.z); o.w = f2b(v.w);
    *(us4*)(featb + (size_t)idx * 4) = o;
}

// ---------------- gather0: bf16 in (width 128) -> bf16 out, NT store ----------------
__global__ void gather0_kernel(const unsigned short* __restrict__ h, const int* __restrict__ row_ptr,
                               const int* __restrict__ csr_src, const float* __restrict__ norm_src,
                               unsigned short* __restrict__ out, int N) {
    constexpr int TPN = F_IN / 4;
    unsigned idx = blockIdx.x * blockDim.x + threadIdx.x;
    if (idx >= (unsigned)N * TPN) return;
    unsigned node = idx / TPN;
    unsigned g = idx % TPN;
    int beg = row_ptr[node], end = row_ptr[node + 1];
    float ax = 0.f, ay = 0.f, az = 0.f, aw = 0.f;
    for (int e = beg; e < end; e++) {
        int s = csr_src[e];
        float ns = norm_src[s];
        const us4 v = *(const us4*)(h + (size_t)s * F_IN + g * 4);
        ax += b2f(v.x) * ns; ay += b2f(v.y) * ns; az += b2f(v.z) * ns; aw += b2f(v.w) * ns;
    }
    us4 o; o.x = f2b(ax); o.y = f2b(ay); o.z = f2b(az); o.w = f2b(aw);
    __builtin_nontemporal_store(o, (us4*)(out + (size_t)node * F_IN + g * 4));
}

// ---------------- gather1: bf16 in (256) with fused BN+ReLU -> bf16 out, NT store ----------
__global__ void gather1_bn_kernel(const unsigned short* __restrict__ h, const int* __restrict__ row_ptr,
                                  const int* __restrict__ csr_src, const float* __restrict__ norm_src,
                                  const float* __restrict__ bna, const float* __restrict__ bnb,
                                  unsigned short* __restrict__ out, int N) {
    constexpr int TPN = F_HID / 4;
    unsigned idx = blockIdx.x * blockDim.x + threadIdx.x;
    if (idx >= (unsigned)N * TPN) return;
    unsigned node = idx / TPN;
    unsigned g = idx % TPN;
    const f32x4 a4 = *(const f32x4*)(bna + g * 4);
    const f32x4 b4 = *(const f32x4*)(bnb + g * 4);
    int beg = row_ptr[node], end = row_ptr[node + 1];
    float ax = 0.f, ay = 0.f, az = 0.f, aw = 0.f;
    for (int e = beg; e < end; e++) {
        int s = csr_src[e];
        float ns = norm_src[s];
        const us4 v = *(const us4*)(h + (size_t)s * F_HID + g * 4);
        ax += fmaxf(b2f(v.x) * a4.x + b4.x, 0.f) * ns;
        ay += fmaxf(b2f(v.y) * a4.y + b4.y, 0.f) * ns;
        az += fmaxf(b2f(v.z) * a4.z + b4.z, 0.f) * ns;
        aw += fmaxf(b2f(v.w) * a4.w + b4.w, 0.f) * ns;
    }
    us4 o; o.x = f2b(ax); o.y = f2b(ay); o.z = f2b(az); o.w = f2b(aw);
    __builtin_nontemporal_store(o, (us4*)(out + (size_t)node * F_HID + g * 4));
}

// ---------------- final gather: f32 in (width 40) + norm_dst + bias -> out ----------------
__global__ void gather_final_kernel(const float* __restrict__ h, const int* __restrict__ row_ptr,
                                    const int* __restrict__ csr_src, const float* __restrict__ norm_src,
                                    const float* __restrict__ norm_dst, const float* __restrict__ bias,
                                    float* __restrict__ out, int N) {
    constexpr int TPN = F_OUT / 4;
    unsigned idx = blockIdx.x * blockDim.x + threadIdx.x;
    if (idx >= (unsigned)N * TPN) return;
    unsigned node = idx / TPN;
    unsigned g = idx % TPN;
    int beg = row_ptr[node], end = row_ptr[node + 1];
    float ax = 0.f, ay = 0.f, az = 0.f, aw = 0.f;
    for (int e = beg; e < end; e++) {
        int s = csr_src[e];
        float ns = norm_src[s];
        const f32x4 v = *(const f32x4*)(h + (size_t)s * F_OUT + g * 4);
        ax += v.x * ns; ay += v.y * ns; az += v.z * ns; aw += v.w * ns;
    }
    float nd = norm_dst[node];
    const f32x4 b = *(const f32x4*)(bias + g * 4);
    f32x4 r;
    r.x = ax * nd + b.x; r.y = ay * nd + b.y; r.z = az * nd + b.z; r.w = aw * nd + b.w;
    __builtin_nontemporal_store(r, (f32x4*)(out + (size_t)node * F_OUT + g * 4));
}

// ---------------- weight transpose+cast: W[K][M] f32 -> Wt[MP][K] bf16 (zero-pad m>=M) ----
template<int K, int M, int MP>
__global__ void wt_kernel(const float* __restrict__ W, unsigned short* __restrict__ Wt) {
    int idx = blockIdx.x * blockDim.x + threadIdx.x;
    if (idx >= MP * K) return;
    int m = idx / K, k = idx % K;
    float v = (m < M) ? W[(size_t)k * M + m] : 0.0f;
    Wt[idx] = f2b(v);
}

// ---------------- BN finalize: col sums -> per-col scale a, shift b ----------------
__global__ void bn_finalize_kernel(const float* __restrict__ sum, const float* __restrict__ sumsq,
                                   const float* __restrict__ gamma, const float* __restrict__ beta,
                                   float* __restrict__ a, float* __restrict__ b) {
    int c = threadIdx.x;
    float invN = 1.0f / (float)NN;
    float mean = sum[c] * invN;
    float var = sumsq[c] * invN - mean * mean;
    float inv = rsqrtf(var + BN_EPS);
    float ac = inv * gamma[c];
    a[c] = ac;
    b[c] = beta[c] - mean * ac;
}

// ---------------- MFMA bf16 GEMM ----------------
// C[N x M_OUT] = A[N x K](bf16) @ Wt^T; SCALE: multiply rows by norm_dst; STATS: fused BN
// column sums (atomics into osum/osumsq); APPLYBN: apply relu(v*bna+bnb) to A during staging.
template<int K, int BN_T, int WM_T, int WN_T, int WAVES_N, bool SCALE, bool BF16OUT, int M_OUT,
         bool STATS, bool APPLYBN>
__global__ __launch_bounds__(256) void mfma_gemm(const unsigned short* __restrict__ A,
                                                 const unsigned short* __restrict__ Wt,
                                                 const float* __restrict__ norm_dst,
                                                 void* __restrict__ C,
                                                 const float* __restrict__ bna,
                                                 const float* __restrict__ bnb,
                                                 float* __restrict__ osum,
                                                 float* __restrict__ osumsq, int N) {
    constexpr int BM = 128, BK = 64, AP = 72;  // +8 bf16 pad: 144 B stride, 2-way banks (free)
    __shared__ unsigned short As[BM * AP];
    __shared__ unsigned short Bs[BN_T * AP];

    const int lane = threadIdx.x & 63;
    const int wave = threadIdx.x >> 6;
    const int wr = wave / WAVES_N, wc = wave % WAVES_N;
    const int quad = lane >> 4, l15 = lane & 15;
    const int r0 = blockIdx.y * BM;
    const int c0 = blockIdx.x * BN_T;
    const int wmb = wr * WM_T * 16;
    const int wnb = wc * WN_T * 16;

    f32x4 acc[WM_T][WN_T] = {};

    for (int k0 = 0; k0 < K; k0 += BK) {
        #pragma unroll
        for (int p = 0; p < BM * (BK / 8) / 256; p++) {
            int c = threadIdx.x + p * 256;
            int row = c >> 3, off = (c & 7) * 8;
            int gr = r0 + row;
            uint4 v = make_uint4(0, 0, 0, 0);
            if (gr < N) {
                v = *(const uint4*)(A + (size_t)gr * K + k0 + off);
                if (APPLYBN) {
                    int kb = k0 + off;
                    const f32x4 a0 = *(const f32x4*)(bna + kb);
                    const f32x4 a1 = *(const f32x4*)(bna + kb + 4);
                    const f32x4 s0 = *(const f32x4*)(bnb + kb);
                    const f32x4 s1 = *(const f32x4*)(bnb + kb + 4);
                    v.x = bn2(v.x, a0.x, s0.x, a0.y, s0.y);
                    v.y = bn2(v.y, a0.z, s0.z, a0.w, s0.w);
                    v.z = bn2(v.z, a1.x, s1.x, a1.y, s1.y);
                    v.w = bn2(v.w, a1.z, s1.z, a1.w, s1.w);
                }
            }
            *(uint4*)(As + row * AP + off) = v;
        }
        #pragma unroll
        for (int p = 0; p < BN_T * (BK / 8) / 256; p++) {
            int c = threadIdx.x + p * 256;
            int m = c >> 3, off = (c & 7) * 8;
            *(uint4*)(Bs + m * AP + off) = *(const uint4*)(Wt + (size_t)(c0 + m) * K + k0 + off);
        }
        __syncthreads();
        #pragma unroll
        for (int kk = 0; kk < BK; kk += 32) {
            short8 af[WM_T], bf[WN_T];
            #pragma unroll
            for (int i = 0; i < WM_T; i++)
                af[i] = *(const short8*)(As + (wmb + i * 16 + l15) * AP + kk + quad * 8);
            #pragma unroll
            for (int j = 0; j < WN_T; j++)
                bf[j] = *(const short8*)(Bs + (wnb + j * 16 + l15) * AP + kk + quad * 8);
            #pragma unroll
            for (int i = 0; i < WM_T; i++)
                #pragma unroll
                for (int j = 0; j < WN_T; j++)
                    acc[i][j] = __builtin_amdgcn_mfma_f32_16x16x32_bf16(af[i], bf[j], acc[i][j], 0, 0, 0);
        }
        __syncthreads();
    }

    // epilogue: C/D layout col=lane&15, row=quad*4+reg
    float s[WN_T] = {}, ss[WN_T] = {};
    #pragma unroll
    for (int i = 0; i < WM_T; i++) {
        #pragma unroll
        for (int r = 0; r < 4; r++) {
            int row = r0 + wmb + i * 16 + quad * 4 + r;
            if (row >= N) continue;
            float scale = SCALE ? norm_dst[row] : 1.0f;
            #pragma unroll
            for (int j = 0; j < WN_T; j++) {
                float v = acc[i][j][r] * scale;
                if (STATS) { s[j] += v; ss[j] += v * v; }
                int col = c0 + wnb + j * 16 + l15;
                if (col < M_OUT) {
                    if (BF16OUT) ((unsigned short*)C)[(size_t)row * M_OUT + col] = f2b(v);
                    else         ((float*)C)[(size_t)row * M_OUT + col] = v;
                }
            }
        }
    }
    if (STATS) {
        #pragma unroll
        for (int j = 0; j < WN_T; j++) {
            float t = s[j], t2 = ss[j];
            t  += __shfl_xor(t, 16);  t  += __shfl_xor(t, 32);
            t2 += __shfl_xor(t2, 16); t2 += __shfl_xor(t2, 32);
            if (quad == 0) {
                int col = c0 + wnb + j * 16 + l15;
                atomicAdd(&osum[col], t);
                atomicAdd(&osumsq[col], t2);
            }
        }
    }
}

extern "C" void kernel_launch(void* const* d_in, const int* in_sizes, int n_in,
                              void* d_out, int out_size, void* d_ws, size_t ws_size,
                              hipStream_t stream) {
    const float* feat  = (const float*)d_in[0];
    const int*   src   = (const int*)d_in[1];
    const int*   dst   = (const int*)d_in[2];
    const float* W0    = (const float*)d_in[3];
    const float* W1    = (const float*)d_in[4];
    const float* W2    = (const float*)d_in[5];
    const float* b2    = (const float*)d_in[6];
    const float* g0    = (const float*)d_in[7];
    const float* beta0 = (const float*)d_in[8];
    const float* g1    = (const float*)d_in[9];
    const float* beta1 = (const float*)d_in[10];
    float* out = (float*)d_out;

    const int N = NN, E = NE;

    // ---- workspace carve (~230 MB; proven budget >= 268 MB)
    char* ws = (char*)d_ws;
    auto alloc_b = [&](size_t bytes) {
        void* p = (void*)ws;
        ws += ((bytes + 255) / 256) * 256;
        return p;
    };
    float* norm_src = (float*)alloc_b((size_t)N * 4);
    float* norm_dst = (float*)alloc_b((size_t)N * 4);
    int*   row_ptr  = (int*)alloc_b((size_t)(N + 1) * 4);
    int*   csr_src  = (int*)alloc_b((size_t)E * 4);
    float* bnsum    = (float*)alloc_b(512 * 4);     // [0:256) sum, [256:512) sumsq
    float* bn_a0    = (float*)alloc_b(256 * 4);
    float* bn_b0    = (float*)alloc_b(256 * 4);
    float* bn_a1    = (float*)alloc_b(256 * 4);
    float* bn_b1    = (float*)alloc_b(256 * 4);
    unsigned short* Wt0 = (unsigned short*)alloc_b((size_t)256 * 128 * 2);
    unsigned short* Wt1 = (unsigned short*)alloc_b((size_t)256 * 256 * 2);
    unsigned short* Wt2 = (unsigned short*)alloc_b((size_t)64 * 256 * 2);
    void* B1 = alloc_b((size_t)N * 512);                  // N x 256 bf16 OR N x 40 f32
    void* B2 = alloc_b((size_t)N * 512);                  // N x 256 bf16
    unsigned short* featb = (unsigned short*)alloc_b((size_t)N * F_IN * 2);
    float* bnsumsq = bnsum + 256;

    unsigned short* B1b = (unsigned short*)B1;
    unsigned short* B2b = (unsigned short*)B2;
    float*          B1f = (float*)B1;

    // CSR-build scratch aliased at head of B1 (dead before gather0 writes B1)
    int* cnt_src  = (int*)B1;
    int* cnt_dst  = cnt_src + N;
    int* fill     = cnt_dst + N;
    int* local    = fill + N;
    int* partials = local + N;

    // ---- CSR build + norms + weight prep + feat cast
    hipMemsetAsync(cnt_src, 0, ((size_t)4 * N + 1024) * 4, stream);
    count_kernel<<<(E + 255) / 256, 256, 0, stream>>>(src, dst, cnt_src, cnt_dst, E);
    norm_kernel<<<(N + 255) / 256, 256, 0, stream>>>(cnt_src, cnt_dst, norm_src, norm_dst, N);
    scan_block_kernel<<<SCAN_B, 256, 0, stream>>>(cnt_dst, local, partials, N);
    scan_partials_kernel<<<1, 1024, 0, stream>>>(partials, SCAN_B);
    scan_add_kernel<<<(N + 255) / 256, 256, 0, stream>>>(local, partials, row_ptr, N);
    fill_kernel<<<(E + 255) / 256, 256, 0, stream>>>(src, dst, row_ptr, fill, csr_src, E);
    wt_kernel<128, 256, 256><<<(256 * 128 + 255) / 256, 256, 0, stream>>>(W0, Wt0);
    wt_kernel<256, 256, 256><<<(256 * 256 + 255) / 256, 256, 0, stream>>>(W1, Wt1);
    wt_kernel<256, 40, 64><<<(64 * 256 + 255) / 256, 256, 0, stream>>>(W2, Wt2);
    cast_feat_kernel<<<((unsigned)N * (F_IN / 4) + 255) / 256, 256, 0, stream>>>(feat, featb);

    const int GB = (N + 127) / 128;

    // ---- layer 0: gather0 -> B1, GEMM0(stats) -> B2(h0_pre), finalize a0/b0
    {
        unsigned total = (unsigned)N * (F_IN / 4);
        gather0_kernel<<<(total + 255) / 256, 256, 0, stream>>>(featb, row_ptr, csr_src, norm_src, B1b, N);
    }
    hipMemsetAsync(bnsum, 0, 512 * 4, stream);
    mfma_gemm<128, 128, 4, 4, 2, true, true, 256, true, false><<<dim3(2, GB), 256, 0, stream>>>(
        B1b, Wt0, norm_dst, B2, nullptr, nullptr, bnsum, bnsumsq, N);
    bn_finalize_kernel<<<1, 256, 0, stream>>>(bnsum, bnsumsq, g0, beta0, bn_a0, bn_b0);

    // ---- layer 1: gather1 (fused BN+ReLU on h0_pre) -> B1, GEMM1(stats) -> B2(h1_pre), finalize
    {
        unsigned total = (unsigned)N * (F_HID / 4);
        gather1_bn_kernel<<<(total + 255) / 256, 256, 0, stream>>>(
            B2b, row_ptr, csr_src, norm_src, bn_a0, bn_b0, B1b, N);
    }
    hipMemsetAsync(bnsum, 0, 512 * 4, stream);
    mfma_gemm<256, 128, 4, 4, 2, true, true, 256, true, false><<<dim3(2, GB), 256, 0, stream>>>(
        B1b, Wt1, norm_dst, B2, nullptr, nullptr, bnsum, bnsumsq, N);
    bn_finalize_kernel<<<1, 256, 0, stream>>>(bnsum, bnsumsq, g1, beta1, bn_a1, bn_b1);

    // ---- layer 2: GEMM2 (fused BN+ReLU on h1_pre in staging) -> B1 f32 [N][40], final gather
    mfma_gemm<256, 64, 2, 4, 1, false, false, 40, false, true><<<dim3(1, GB), 256, 0, stream>>>(
        B2b, Wt2, nullptr, B1, bn_a1, bn_b1, nullptr, nullptr, N);
    {
        unsigned total = (unsigned)N * (F_OUT / 4);
        gather_final_kernel<<<(total + 255) / 256, 256, 0, stream>>>(
            B1f, row_ptr, csr_src, norm_src, norm_dst, b2, out, N);
    }
}